// Round 4
// 228.790 us; speedup vs baseline: 1.2865x; 1.2865x over previous
//
#include <hip/hip_runtime.h>
#include <math.h>

#define BOX   256
#define NPTS  50000
#define LATD  10
#define NEUR  32
#define NLAY  3
#define BATCH 16

#define MTPB  256
#define MBLKX ((NPTS + MTPB - 1)/MTPB)     // 196 blocks/image, 1 pt/thread

#define PTPB  256
#define PBLKX ((NPTS + PTPB - 1)/PTPB)     // 196

#define CELLS_X 64                          // 4x4-px cells
#define CELLS   (CELLS_X*CELLS_X)           // 4096
#define PREF_STRIDE 4104
#define CHUNK   256
#define WCAP    4608

#define IMG_ELEMS (BATCH*BOX*BOX)
#define OFF_IMG2  (IMG_ELEMS)
#define OFF_PROJ  (2*IMG_ELEMS)
#define OFF_POS   (OFF_PROJ + BATCH*NPTS*2)
#define OFF_RES   (OFF_POS  + BATCH*NPTS*3)

// ws ints: counts[16*4096] | n_work[16] | prefix[16*4104] | work[16*4608] | aux[16*50000]
// then (16B aligned): recs float4[16*50000]   -> ~16.8 MB total
#define WS_COUNTS 0
#define WS_NWORK  (BATCH*CELLS)
#define WS_PREFIX (WS_NWORK + BATCH)
#define WS_WORK   (WS_PREFIX + BATCH*PREF_STRIDE)
#define WS_AUX    (WS_WORK + BATCH*WCAP)
#define WS_INTS   (WS_AUX + BATCH*NPTS)

// LDS h-tile row stride in dwords: 32 h cols + pad to 36 (144 B rows, 16B-aligned)
#define HSTR 36

typedef _Float16 f16x8 __attribute__((ext_vector_type(8)));
typedef float    f32x4 __attribute__((ext_vector_type(4)));

__device__ __forceinline__ float fast_tanh(float x) {
    return 1.0f - 2.0f / (__expf(2.0f * x) + 1.0f);
}

// RNE float->fp16 pack (v_cvt_f16_f32 is RNE; fp16 half-ulp 2^-11 vs bf16 2^-8)
__device__ __forceinline__ f16x8 pack8h(f32x4 a, f32x4 b) {
    f16x8 v;
    v[0] = (_Float16)a[0]; v[1] = (_Float16)a[1];
    v[2] = (_Float16)a[2]; v[3] = (_Float16)a[3];
    v[4] = (_Float16)b[0]; v[5] = (_Float16)b[1];
    v[6] = (_Float16)b[2]; v[7] = (_Float16)b[3];
    return v;
}

// ---- kernel A: fused MLP. lin0 + lin1a/b in VALU; 3 deform layers via
//      mfma_f32_16x16x32_f16 (A row=lane&15 k0=rq*8 from ds_read_b128 pairs,
//      B col=lane&15 preloaded in VGPRs, D: col=lane&15 row=4rq+reg [m89]).
//      fp32 residual/bias/acc; fp16 only on matmul operands. Then histogram+claim.
__global__ __launch_bounds__(MTPB) void mlp_bin(
    const float* __restrict__ z, const float* __restrict__ r,
    const float* __restrict__ pos_param, const float* __restrict__ amp,
    const float* __restrict__ lin0_w, const float* __restrict__ deform_w,
    const float* __restrict__ deform_b, const float* __restrict__ lin1a_w,
    const float* __restrict__ lin1b_w, const float* __restrict__ linamp_w,
    const float* __restrict__ linamp_b, const int* __restrict__ dflag,
    float* __restrict__ out, int* __restrict__ counts, int* __restrict__ aux)
{
    // 4 wave-private h-tiles [64][HSTR] fp32 + zpart[32]; s_cnt (4096 ints)
    // unioned onto tiles 0/1, used only after all tile reads are done.
    __shared__ __align__(16) float s_mem[4*64*HSTR + NEUR];
    int*   s_cnt = (int*)s_mem;
    float* s_z   = s_mem + 4*64*HSTR;

    const int b     = blockIdx.y;
    const int tid   = threadIdx.x;
    const int wave  = tid >> 6;
    const int lane  = tid & 63;
    const int cfrag = lane & 15;           // A row / B col / D col
    const int rq    = lane >> 4;
    const int k0    = rq * 8;              // fragment K offset
    float* __restrict__ s_hw = s_mem + wave*64*HSTR;

    if (tid < NEUR) {
        float acc = 0.f;
        #pragma unroll
        for (int j = 0; j < LATD-1; j++)
            acc = fmaf(lin0_w[tid*12 + 3 + j], z[b*LATD + j], acc);
        s_z[tid] = acc;
    }
    __syncthreads();

    const int n  = blockIdx.x*MTPB + tid;
    const bool v0 = (n < NPTS);
    const int m0 = v0 ? n : (NPTS-1);
    const int dd = *dflag;

    const float p0w = pos_param[m0*3+0], p1w = pos_param[m0*3+1], p2w = pos_param[m0*3+2];

    float res0 = 0.f, res1 = 0.f, res2 = 0.f;

    if (dd > 0) {
        // ---- preload deform weights as fp16 B-fragments + biases ----
        f16x8 bfrag[NLAY][2];
        float bias_c[NLAY][2];
        #pragma unroll
        for (int l = 0; l < NLAY; ++l) {
            #pragma unroll
            for (int nt = 0; nt < 2; ++nt) {
                const int c = cfrag + 16*nt;
                const float* wp = deform_w + l*NEUR*NEUR + c*NEUR + k0;
                bfrag[l][nt]  = pack8h(*(const f32x4*)wp, *(const f32x4*)(wp + 4));
                bias_c[l][nt] = deform_b[l*NEUR + c];
            }
        }

        // ---- lin0 in VALU: thread writes its own tile row (8 x b128) ----
        #pragma unroll
        for (int o4 = 0; o4 < 8; ++o4) {
            f32x4 hv;
            #pragma unroll
            for (int jj = 0; jj < 4; ++jj) {
                const int o = o4*4 + jj;
                hv[jj] = fmaf(lin0_w[o*12+0], p0w,
                         fmaf(lin0_w[o*12+1], p1w,
                         fmaf(lin0_w[o*12+2], p2w, s_z[o])));
            }
            *(f32x4*)&s_hw[lane*HSTR + o4*4] = hv;
        }
        __syncthreads();

        // ---- 3 residual relu layers via MFMA ----
        const f32x4 zc = {0.f, 0.f, 0.f, 0.f};
        #pragma unroll
        for (int l = 0; l < NLAY; ++l) {
            f16x8 af[4];
            float rs0[4][4], rs1[4][4];
            #pragma unroll
            for (int mt = 0; mt < 4; ++mt) {
                const float* ap = &s_hw[(16*mt + cfrag)*HSTR + k0];
                af[mt] = pack8h(*(const f32x4*)ap, *(const f32x4*)(ap + 4));
                const int rb = (16*mt + 4*rq)*HSTR + cfrag;
                #pragma unroll
                for (int rr = 0; rr < 4; ++rr) {
                    rs0[mt][rr] = s_hw[rb + rr*HSTR];
                    rs1[mt][rr] = s_hw[rb + rr*HSTR + 16];
                }
            }
            f32x4 ac0[4], ac1[4];
            #pragma unroll
            for (int mt = 0; mt < 4; ++mt) {
                ac0[mt] = __builtin_amdgcn_mfma_f32_16x16x32_f16(af[mt], bfrag[l][0], zc, 0, 0, 0);
                ac1[mt] = __builtin_amdgcn_mfma_f32_16x16x32_f16(af[mt], bfrag[l][1], zc, 0, 0, 0);
            }
            __syncthreads();               // all tile reads done before overwrite
            const float b0l = bias_c[l][0], b1l = bias_c[l][1];
            #pragma unroll
            for (int mt = 0; mt < 4; ++mt) {
                const int rb = (16*mt + 4*rq)*HSTR + cfrag;
                #pragma unroll
                for (int rr = 0; rr < 4; ++rr) {
                    s_hw[rb + rr*HSTR]      = fmaxf(ac0[mt][rr] + b0l, 0.f) + rs0[mt][rr];
                    s_hw[rb + rr*HSTR + 16] = fmaxf(ac1[mt][rr] + b1l, 0.f) + rs1[mt][rr];
                }
            }
            __syncthreads();               // writes visible before next layer reads
        }

        // ---- lin1a + tanh + lin1b in VALU (thread reads its own row) ----
        float t0 = 0.f, t1 = 0.f, t2 = 0.f;
        #pragma unroll
        for (int ch = 0; ch < 8; ++ch) {
            const f32x4 hv = *(const f32x4*)&s_hw[lane*HSTR + ch*4];
            #pragma unroll
            for (int jj = 0; jj < 4; ++jj) {
                const int j = ch*4 + jj;
                t0 = fmaf(lin1a_w[0*NEUR + j], hv[jj], t0);
                t1 = fmaf(lin1a_w[1*NEUR + j], hv[jj], t1);
                t2 = fmaf(lin1a_w[2*NEUR + j], hv[jj], t2);
            }
        }
        t0 = fast_tanh(t0); t1 = fast_tanh(t1); t2 = fast_tanh(t2);
        res0 = fmaf(t0, lin1b_w[0], fmaf(t1, lin1b_w[1], t2*lin1b_w[2]));
        res1 = fmaf(t0, lin1b_w[3], fmaf(t1, lin1b_w[4], t2*lin1b_w[5]));
        res2 = fmaf(t0, lin1b_w[6], fmaf(t1, lin1b_w[7], t2*lin1b_w[8]));
    }

    // ---- epilogue: project, write outputs, bin ----
    const float r00 = r[b*9+0], r01 = r[b*9+1];
    const float r10 = r[b*9+3], r11 = r[b*9+4];
    const float r20 = r[b*9+6], r21 = r[b*9+7];

    int cell = 0;
    if (v0) {
        const float pos0 = p0w + res0, pos1 = p1w + res1, pos2 = p2w + res2;
        const float pj0 = fmaf(pos0, r00, fmaf(pos1, r10, pos2*r20));
        const float pj1 = fmaf(pos0, r01, fmaf(pos1, r11, pos2*r21));
        const long long bn = (long long)b*NPTS + n;
        out[OFF_PROJ + bn*2 + 0] = pj0;  out[OFF_PROJ + bn*2 + 1] = pj1;
        out[OFF_POS  + bn*3 + 0] = pos0; out[OFF_POS  + bn*3 + 1] = pos1;
        out[OFF_POS  + bn*3 + 2] = pos2;
        out[OFF_RES  + bn*3 + 0] = res0; out[OFF_RES + bn*3 + 1] = res1;
        out[OFF_RES  + bn*3 + 2] = res2;
        const float px0 = (pj0 + 0.5f) * (float)(BOX-1);
        const float px1 = (pj1 + 0.5f) * (float)(BOX-1);
        const int c0 = (int)fminf(fmaxf(floorf(px0 + 0.5f), 0.f), 255.f);
        const int c1 = (int)fminf(fmaxf(floorf(px1 + 0.5f), 0.f), 255.f);
        cell = (c0>>2)*CELLS_X + (c1>>2);
    }

    __syncthreads();                       // all h-tile reads done -> reuse as s_cnt
    for (int i = tid; i < CELLS; i += MTPB) s_cnt[i] = 0;
    __syncthreads();
    int rank = 0;
    if (v0) rank = atomicAdd(&s_cnt[cell], 1);
    __syncthreads();
    // claim global bases: one atomic per non-empty cell per block; s_cnt becomes base
    for (int c = tid; c < CELLS; c += MTPB) {
        const int cnt = s_cnt[c];
        if (cnt > 0) s_cnt[c] = atomicAdd(&counts[b*CELLS + c], cnt);
    }
    __syncthreads();
    if (v0) aux[b*NPTS + n] = (cell << 16) | (s_cnt[cell] + rank);
}

// ------- kernel B: prefix scan of 4096 cells per image + fused work-item build -------
__global__ __launch_bounds__(1024) void scan_cells(
    const int* __restrict__ counts, int* __restrict__ prefix,
    int* __restrict__ n_work, int* __restrict__ work)
{
    __shared__ int lds[1024];
    __shared__ int s_nw;
    const int img = blockIdx.x, t = threadIdx.x;
    if (t == 0) s_nw = 0;
    const int4 v = ((const int4*)(counts + img*CELLS))[t];
    const int s0 = v.x, s1 = s0 + v.y, s2 = s1 + v.z, s3 = s2 + v.w;
    lds[t] = s3;
    __syncthreads();
    #pragma unroll 1
    for (int off = 1; off < 1024; off <<= 1) {
        const int add = (t >= off) ? lds[t - off] : 0;
        __syncthreads();
        lds[t] += add;
        __syncthreads();
    }
    const int incl = lds[t];
    const int base = incl - s3;
    ((int4*)(prefix + img*PREF_STRIDE))[t] = make_int4(base, base+s0, base+s1, base+s2);
    if (t == 1023) prefix[img*PREF_STRIDE + CELLS] = incl;

    // fused build_work: each thread owns cells 4t..4t+3 with counts v.x..v.w
    const int cnts[4] = { v.x, v.y, v.z, v.w };
    #pragma unroll
    for (int i = 0; i < 4; i++) {
        const int cnt = cnts[i];
        if (cnt > 0) {
            const int c = 4*t + i;
            const int nch = (cnt + CHUNK - 1)/CHUNK;
            const int wb = atomicAdd(&s_nw, nch);
            for (int k = 0; k < nch; k++) work[img*WCAP + wb + k] = (c << 8) | k;
        }
    }
    __syncthreads();
    if (t == 0) n_work[img] = s_nw;
}

// ------- kernel C: place records at final cell-sorted positions -------
__global__ __launch_bounds__(PTPB) void place(
    const float* __restrict__ z, const float* __restrict__ amp,
    const float* __restrict__ linamp_w, const float* __restrict__ linamp_b,
    const float* __restrict__ out, const int* __restrict__ prefix,
    const int* __restrict__ aux, float4* __restrict__ recs)
{
    const int b = blockIdx.y;
    const int n = blockIdx.x*PTPB + threadIdx.x;
    if (n >= NPTS) return;

    const long long bn = (long long)b*NPTS + n;
    const float pj0 = out[OFF_PROJ + bn*2 + 0];
    const float pj1 = out[OFF_PROJ + bn*2 + 1];
    const float lo = fmaf(z[b*LATD + LATD-1], linamp_w[n], linamp_b[n]);
    const float a  = amp[0] / (1.0f + __expf(-lo));
    const float px0 = (pj0 + 0.5f) * (float)(BOX-1);
    const float px1 = (pj1 + 0.5f) * (float)(BOX-1);

    const int av  = aux[b*NPTS + n];
    const int cell = av >> 16, wr = av & 0xFFFF;
    const int dst  = prefix[b*PREF_STRIDE + cell] + wr;
    recs[(long long)b*NPTS + dst] = make_float4(px0, px1, a, 0.f);
}

// -------- kernel D: one wave per chunk; scalar record loads (8-deep); 2-exp + int masks --------
__global__ __launch_bounds__(256) void gather_work(
    const float4* __restrict__ recs, const int* __restrict__ prefix,
    const int* __restrict__ n_work, const int* __restrict__ work,
    float* __restrict__ out)
{
    const int b    = blockIdx.y;
    const int wave = blockIdx.x*4 + (threadIdx.x >> 6);   // 0..255
    const int lane = threadIdx.x & 63;
    const int nw   = n_work[b];

    const int* __restrict__ P = prefix + b*PREF_STRIDE;
    const float4* __restrict__ R = recs + (long long)b*NPTS;
    float* __restrict__ img = out + (size_t)b*BOX*BOX;
    const float Kc  = -0.32059884f;                // -log2(e)/(2*sig^2)
    const float K8  = 8.0f  * Kc;
    const float K16 = 16.0f * Kc;
    const float C32 = 0.00081582472f;              // 2^(32*Kc)

    for (int it = wave; it < nw; it += 256) {
        const int wd   = __builtin_amdgcn_readfirstlane(work[b*WCAP + it]);
        const int cell = wd >> 8, kch = wd & 255;
        const int s = P[cell] + kch*CHUNK;          // scalar (cell uniform)
        const int e = min(P[cell+1], s + CHUNK);

        const int cy = cell >> 6, cx = cell & 63;
        const int col = lane & 15, r0 = lane >> 4;
        const int gx  = 4*cx - 4 + col;
        const int gy0 = 4*cy - 4 + r0;
        const float xf  = (float)gx;
        const float y0f = (float)gy0;
        const float fr0 = (float)r0;
        const float cy4 = (float)(4*cy);

        float a0 = 0.f, a1 = 0.f, a2 = 0.f;
        #pragma unroll 8
        for (int rr = s; rr < e; ++rr) {
            const float4 rc = R[rr];                // uniform addr -> s_load_dwordx4
            const float ry = rc.x, rx = rc.y, ra = rc.z;

            const float dx = xf - rx;
            float aex = ra * exp2f((dx*dx)*Kc);
            aex = (dx > -4.5f && dx <= 4.5f) ? aex : 0.f;

            const float dy = y0f - ry;
            const float e0 = exp2f((dy*dy)*Kc);
            // clamp exponent: no-op for in-cell records (exp <= ~17); prevents
            // inf (and 0*inf=NaN) if a record ever lands wildly out of range
            const float u  = exp2f(fminf(fmaf(dy, K8, K16), 126.f));
            const float e1 = e0 * u;
            const float e2 = e1 * (u * C32);
            const float st = floorf(ry + 0.5f) - cy4;
            const float w0 = (fr0 >= st) ? e0 : 0.f;
            const float w2 = (fr0 <= st) ? e2 : 0.f;
            a0 = fmaf(w0, aex, a0);
            a1 = fmaf(e1, aex, a1);
            a2 = fmaf(w2, aex, a2);
        }

        if (gx >= 0 && gx < BOX) {
            if (a0 != 0.f && gy0 >= 0)      atomicAdd(&img[ gy0     *BOX + gx], a0);
            if (a1 != 0.f)                  atomicAdd(&img[(gy0 + 4)*BOX + gx], a1);
            if (a2 != 0.f && gy0 + 8 < BOX) atomicAdd(&img[(gy0 + 8)*BOX + gx], a2);
        }
    }
}

__global__ __launch_bounds__(256) void copy_img(const float4* __restrict__ src,
                                                float4* __restrict__ dst, int n4)
{
    int i = blockIdx.x*blockDim.x + threadIdx.x;
    if (i < n4) dst[i] = src[i];
}

extern "C" void kernel_launch(void* const* d_in, const int* in_sizes, int n_in,
                              void* d_out, int out_size, void* d_ws, size_t ws_size,
                              hipStream_t stream)
{
    const float* z        = (const float*)d_in[0];
    const float* r        = (const float*)d_in[1];
    const float* posp     = (const float*)d_in[2];
    const float* amp      = (const float*)d_in[3];
    const float* lin0_w   = (const float*)d_in[4];
    const float* deform_w = (const float*)d_in[5];
    const float* deform_b = (const float*)d_in[6];
    const float* lin1a_w  = (const float*)d_in[7];
    const float* lin1b_w  = (const float*)d_in[8];
    const float* linamp_w = (const float*)d_in[9];
    const float* linamp_b = (const float*)d_in[10];
    const int*   dflag    = (const int*)d_in[11];
    float* out = (float*)d_out;

    int* ws_i    = (int*)d_ws;
    int* counts  = ws_i + WS_COUNTS;
    int* n_work  = ws_i + WS_NWORK;
    int* prefix  = ws_i + WS_PREFIX;
    int* work    = ws_i + WS_WORK;
    int* aux     = ws_i + WS_AUX;
    float4* recs = (float4*)((char*)d_ws + (size_t)WS_INTS*sizeof(int));

    hipMemsetAsync(counts, 0, (size_t)(BATCH*CELLS + BATCH)*sizeof(int), stream);
    hipMemsetAsync(out, 0, (size_t)IMG_ELEMS*sizeof(float), stream);

    dim3 gridM(MBLKX, BATCH);
    mlp_bin<<<gridM, MTPB, 0, stream>>>(z, r, posp, amp, lin0_w, deform_w, deform_b,
                                        lin1a_w, lin1b_w, linamp_w, linamp_b, dflag,
                                        out, counts, aux);

    scan_cells<<<BATCH, 1024, 0, stream>>>(counts, prefix, n_work, work);

    dim3 gridP(PBLKX, BATCH);
    place<<<gridP, PTPB, 0, stream>>>(z, amp, linamp_w, linamp_b, out, prefix, aux, recs);

    dim3 gridG(64, BATCH);
    gather_work<<<gridG, 256, 0, stream>>>(recs, prefix, n_work, work, out);

    const int n4 = IMG_ELEMS/4;
    copy_img<<<(n4 + 255)/256, 256, 0, stream>>>((const float4*)out,
                                                 (float4*)(out + OFF_IMG2), n4);
}

// Round 5
// 219.843 us; speedup vs baseline: 1.3389x; 1.0407x over previous
//
#include <hip/hip_runtime.h>
#include <math.h>

#define BOX   256
#define NPTS  50000
#define LATD  10
#define NEUR  32
#define NLAY  3
#define BATCH 16

#define MTPB  256
#define MBLKX ((NPTS + MTPB - 1)/MTPB)     // 196 blocks/image, 1 pt/thread

#define PTPB  256
#define PBLKX ((NPTS + PTPB - 1)/PTPB)     // 196

#define CELLS_X 64                          // 4x4-px cells
#define CELLS   (CELLS_X*CELLS_X)           // 4096
#define PREF_STRIDE 4104
#define CHUNK   128                         // finer chunks: worst-case nw = 4096+391 <= WCAP
#define WCAP    4608

// gather grid: 256 blocks/image * 4 waves = 1024 waves/image
#define GBLK    256
#define GSTRIDE (GBLK*4)

#define IMG_ELEMS (BATCH*BOX*BOX)
#define OFF_IMG2  (IMG_ELEMS)
#define OFF_PROJ  (2*IMG_ELEMS)
#define OFF_POS   (OFF_PROJ + BATCH*NPTS*2)
#define OFF_RES   (OFF_POS  + BATCH*NPTS*3)

// ws ints: counts[16*4096] | n_work[16] | prefix[16*4104] | work[16*4608] | aux[16*50000]
// then (16B aligned): recs float4[16*50000]   -> ~16.8 MB total
#define WS_COUNTS 0
#define WS_NWORK  (BATCH*CELLS)
#define WS_PREFIX (WS_NWORK + BATCH)
#define WS_WORK   (WS_PREFIX + BATCH*PREF_STRIDE)
#define WS_AUX    (WS_WORK + BATCH*WCAP)
#define WS_INTS   (WS_AUX + BATCH*NPTS)

// LDS h-tile row stride in dwords: 32 h cols + pad to 36 (144 B rows, 16B-aligned)
#define HSTR 36

typedef _Float16 f16x8 __attribute__((ext_vector_type(8)));
typedef float    f32x4 __attribute__((ext_vector_type(4)));

__device__ __forceinline__ float fast_tanh(float x) {
    return 1.0f - 2.0f / (__expf(2.0f * x) + 1.0f);
}

// RNE float->fp16 pack (v_cvt_f16_f32 is RNE; fp16 half-ulp 2^-11 vs bf16 2^-8)
__device__ __forceinline__ f16x8 pack8h(f32x4 a, f32x4 b) {
    f16x8 v;
    v[0] = (_Float16)a[0]; v[1] = (_Float16)a[1];
    v[2] = (_Float16)a[2]; v[3] = (_Float16)a[3];
    v[4] = (_Float16)b[0]; v[5] = (_Float16)b[1];
    v[6] = (_Float16)b[2]; v[7] = (_Float16)b[3];
    return v;
}

// ---- kernel A: fused MLP. lin0 + lin1a/b in VALU; 3 deform layers via
//      mfma_f32_16x16x32_f16 (A row=lane&15 k0=rq*8 from ds_read_b128 pairs,
//      B col=lane&15 preloaded in VGPRs, D: col=lane&15 row=4rq+reg [m89]).
//      fp32 residual/bias/acc; fp16 only on matmul operands. Then histogram+claim.
__global__ __launch_bounds__(MTPB) void mlp_bin(
    const float* __restrict__ z, const float* __restrict__ r,
    const float* __restrict__ pos_param, const float* __restrict__ amp,
    const float* __restrict__ lin0_w, const float* __restrict__ deform_w,
    const float* __restrict__ deform_b, const float* __restrict__ lin1a_w,
    const float* __restrict__ lin1b_w, const float* __restrict__ linamp_w,
    const float* __restrict__ linamp_b, const int* __restrict__ dflag,
    float* __restrict__ out, int* __restrict__ counts, int* __restrict__ aux)
{
    // 4 wave-private h-tiles [64][HSTR] fp32 + zpart[32]; s_cnt (4096 ints)
    // unioned onto tiles 0/1, used only after all tile reads are done.
    __shared__ __align__(16) float s_mem[4*64*HSTR + NEUR];
    int*   s_cnt = (int*)s_mem;
    float* s_z   = s_mem + 4*64*HSTR;

    const int b     = blockIdx.y;
    const int tid   = threadIdx.x;
    const int wave  = tid >> 6;
    const int lane  = tid & 63;
    const int cfrag = lane & 15;           // A row / B col / D col
    const int rq    = lane >> 4;
    const int k0    = rq * 8;              // fragment K offset
    float* __restrict__ s_hw = s_mem + wave*64*HSTR;

    if (tid < NEUR) {
        float acc = 0.f;
        #pragma unroll
        for (int j = 0; j < LATD-1; j++)
            acc = fmaf(lin0_w[tid*12 + 3 + j], z[b*LATD + j], acc);
        s_z[tid] = acc;
    }
    __syncthreads();

    const int n  = blockIdx.x*MTPB + tid;
    const bool v0 = (n < NPTS);
    const int m0 = v0 ? n : (NPTS-1);
    const int dd = *dflag;

    const float p0w = pos_param[m0*3+0], p1w = pos_param[m0*3+1], p2w = pos_param[m0*3+2];

    float res0 = 0.f, res1 = 0.f, res2 = 0.f;

    if (dd > 0) {
        // ---- preload deform weights as fp16 B-fragments + biases ----
        f16x8 bfrag[NLAY][2];
        float bias_c[NLAY][2];
        #pragma unroll
        for (int l = 0; l < NLAY; ++l) {
            #pragma unroll
            for (int nt = 0; nt < 2; ++nt) {
                const int c = cfrag + 16*nt;
                const float* wp = deform_w + l*NEUR*NEUR + c*NEUR + k0;
                bfrag[l][nt]  = pack8h(*(const f32x4*)wp, *(const f32x4*)(wp + 4));
                bias_c[l][nt] = deform_b[l*NEUR + c];
            }
        }

        // ---- lin0 in VALU: thread writes its own tile row (8 x b128) ----
        #pragma unroll
        for (int o4 = 0; o4 < 8; ++o4) {
            f32x4 hv;
            #pragma unroll
            for (int jj = 0; jj < 4; ++jj) {
                const int o = o4*4 + jj;
                hv[jj] = fmaf(lin0_w[o*12+0], p0w,
                         fmaf(lin0_w[o*12+1], p1w,
                         fmaf(lin0_w[o*12+2], p2w, s_z[o])));
            }
            *(f32x4*)&s_hw[lane*HSTR + o4*4] = hv;
        }
        __syncthreads();

        // ---- 3 residual relu layers via MFMA ----
        const f32x4 zc = {0.f, 0.f, 0.f, 0.f};
        #pragma unroll
        for (int l = 0; l < NLAY; ++l) {
            f16x8 af[4];
            float rs0[4][4], rs1[4][4];
            #pragma unroll
            for (int mt = 0; mt < 4; ++mt) {
                const float* ap = &s_hw[(16*mt + cfrag)*HSTR + k0];
                af[mt] = pack8h(*(const f32x4*)ap, *(const f32x4*)(ap + 4));
                const int rb = (16*mt + 4*rq)*HSTR + cfrag;
                #pragma unroll
                for (int rr = 0; rr < 4; ++rr) {
                    rs0[mt][rr] = s_hw[rb + rr*HSTR];
                    rs1[mt][rr] = s_hw[rb + rr*HSTR + 16];
                }
            }
            f32x4 ac0[4], ac1[4];
            #pragma unroll
            for (int mt = 0; mt < 4; ++mt) {
                ac0[mt] = __builtin_amdgcn_mfma_f32_16x16x32_f16(af[mt], bfrag[l][0], zc, 0, 0, 0);
                ac1[mt] = __builtin_amdgcn_mfma_f32_16x16x32_f16(af[mt], bfrag[l][1], zc, 0, 0, 0);
            }
            __syncthreads();               // all tile reads done before overwrite
            const float b0l = bias_c[l][0], b1l = bias_c[l][1];
            #pragma unroll
            for (int mt = 0; mt < 4; ++mt) {
                const int rb = (16*mt + 4*rq)*HSTR + cfrag;
                #pragma unroll
                for (int rr = 0; rr < 4; ++rr) {
                    s_hw[rb + rr*HSTR]      = fmaxf(ac0[mt][rr] + b0l, 0.f) + rs0[mt][rr];
                    s_hw[rb + rr*HSTR + 16] = fmaxf(ac1[mt][rr] + b1l, 0.f) + rs1[mt][rr];
                }
            }
            __syncthreads();               // writes visible before next layer reads
        }

        // ---- lin1a + tanh + lin1b in VALU (thread reads its own row) ----
        float t0 = 0.f, t1 = 0.f, t2 = 0.f;
        #pragma unroll
        for (int ch = 0; ch < 8; ++ch) {
            const f32x4 hv = *(const f32x4*)&s_hw[lane*HSTR + ch*4];
            #pragma unroll
            for (int jj = 0; jj < 4; ++jj) {
                const int j = ch*4 + jj;
                t0 = fmaf(lin1a_w[0*NEUR + j], hv[jj], t0);
                t1 = fmaf(lin1a_w[1*NEUR + j], hv[jj], t1);
                t2 = fmaf(lin1a_w[2*NEUR + j], hv[jj], t2);
            }
        }
        t0 = fast_tanh(t0); t1 = fast_tanh(t1); t2 = fast_tanh(t2);
        res0 = fmaf(t0, lin1b_w[0], fmaf(t1, lin1b_w[1], t2*lin1b_w[2]));
        res1 = fmaf(t0, lin1b_w[3], fmaf(t1, lin1b_w[4], t2*lin1b_w[5]));
        res2 = fmaf(t0, lin1b_w[6], fmaf(t1, lin1b_w[7], t2*lin1b_w[8]));
    }

    // ---- epilogue: project, write outputs, bin ----
    const float r00 = r[b*9+0], r01 = r[b*9+1];
    const float r10 = r[b*9+3], r11 = r[b*9+4];
    const float r20 = r[b*9+6], r21 = r[b*9+7];

    int cell = 0;
    if (v0) {
        const float pos0 = p0w + res0, pos1 = p1w + res1, pos2 = p2w + res2;
        const float pj0 = fmaf(pos0, r00, fmaf(pos1, r10, pos2*r20));
        const float pj1 = fmaf(pos0, r01, fmaf(pos1, r11, pos2*r21));
        const long long bn = (long long)b*NPTS + n;
        out[OFF_PROJ + bn*2 + 0] = pj0;  out[OFF_PROJ + bn*2 + 1] = pj1;
        out[OFF_POS  + bn*3 + 0] = pos0; out[OFF_POS  + bn*3 + 1] = pos1;
        out[OFF_POS  + bn*3 + 2] = pos2;
        out[OFF_RES  + bn*3 + 0] = res0; out[OFF_RES + bn*3 + 1] = res1;
        out[OFF_RES  + bn*3 + 2] = res2;
        const float px0 = (pj0 + 0.5f) * (float)(BOX-1);
        const float px1 = (pj1 + 0.5f) * (float)(BOX-1);
        const int c0 = (int)fminf(fmaxf(floorf(px0 + 0.5f), 0.f), 255.f);
        const int c1 = (int)fminf(fmaxf(floorf(px1 + 0.5f), 0.f), 255.f);
        cell = (c0>>2)*CELLS_X + (c1>>2);
    }

    __syncthreads();                       // all h-tile reads done -> reuse as s_cnt
    for (int i = tid; i < CELLS; i += MTPB) s_cnt[i] = 0;
    __syncthreads();
    int rank = 0;
    if (v0) rank = atomicAdd(&s_cnt[cell], 1);
    __syncthreads();
    // claim global bases: one atomic per non-empty cell per block; s_cnt becomes base
    for (int c = tid; c < CELLS; c += MTPB) {
        const int cnt = s_cnt[c];
        if (cnt > 0) s_cnt[c] = atomicAdd(&counts[b*CELLS + c], cnt);
    }
    __syncthreads();
    if (v0) aux[b*NPTS + n] = (cell << 16) | (s_cnt[cell] + rank);
}

// ------- kernel B: prefix scan of 4096 cells per image + fused work-item build -------
__global__ __launch_bounds__(1024) void scan_cells(
    const int* __restrict__ counts, int* __restrict__ prefix,
    int* __restrict__ n_work, int* __restrict__ work)
{
    __shared__ int lds[1024];
    __shared__ int s_nw;
    const int img = blockIdx.x, t = threadIdx.x;
    if (t == 0) s_nw = 0;
    const int4 v = ((const int4*)(counts + img*CELLS))[t];
    const int s0 = v.x, s1 = s0 + v.y, s2 = s1 + v.z, s3 = s2 + v.w;
    lds[t] = s3;
    __syncthreads();
    #pragma unroll 1
    for (int off = 1; off < 1024; off <<= 1) {
        const int add = (t >= off) ? lds[t - off] : 0;
        __syncthreads();
        lds[t] += add;
        __syncthreads();
    }
    const int incl = lds[t];
    const int base = incl - s3;
    ((int4*)(prefix + img*PREF_STRIDE))[t] = make_int4(base, base+s0, base+s1, base+s2);
    if (t == 1023) prefix[img*PREF_STRIDE + CELLS] = incl;

    // fused build_work: each thread owns cells 4t..4t+3 with counts v.x..v.w
    // work item = (cell << 9) | chunk_idx   (chunk_idx < 512 since CHUNK=128)
    const int cnts[4] = { v.x, v.y, v.z, v.w };
    #pragma unroll
    for (int i = 0; i < 4; i++) {
        const int cnt = cnts[i];
        if (cnt > 0) {
            const int c = 4*t + i;
            const int nch = (cnt + CHUNK - 1)/CHUNK;
            const int wb = atomicAdd(&s_nw, nch);
            for (int k = 0; k < nch; k++) work[img*WCAP + wb + k] = (c << 9) | k;
        }
    }
    __syncthreads();
    if (t == 0) n_work[img] = s_nw;
}

// ------- kernel C: place records at final cell-sorted positions -------
__global__ __launch_bounds__(PTPB) void place(
    const float* __restrict__ z, const float* __restrict__ amp,
    const float* __restrict__ linamp_w, const float* __restrict__ linamp_b,
    const float* __restrict__ out, const int* __restrict__ prefix,
    const int* __restrict__ aux, float4* __restrict__ recs)
{
    const int b = blockIdx.y;
    const int n = blockIdx.x*PTPB + threadIdx.x;
    if (n >= NPTS) return;

    const long long bn = (long long)b*NPTS + n;
    const float pj0 = out[OFF_PROJ + bn*2 + 0];
    const float pj1 = out[OFF_PROJ + bn*2 + 1];
    const float lo = fmaf(z[b*LATD + LATD-1], linamp_w[n], linamp_b[n]);
    const float a  = amp[0] / (1.0f + __expf(-lo));
    const float px0 = (pj0 + 0.5f) * (float)(BOX-1);
    const float px1 = (pj1 + 0.5f) * (float)(BOX-1);

    const int av  = aux[b*NPTS + n];
    const int cell = av >> 16, wr = av & 0xFFFF;
    const int dst  = prefix[b*PREF_STRIDE + cell] + wr;
    recs[(long long)b*NPTS + dst] = make_float4(px0, px1, a, 0.f);
}

// -------- kernel D: one wave per chunk; scalar record loads (8-deep); 2-exp + int masks --------
__global__ __launch_bounds__(256) void gather_work(
    const float4* __restrict__ recs, const int* __restrict__ prefix,
    const int* __restrict__ n_work, const int* __restrict__ work,
    float* __restrict__ out)
{
    const int b    = blockIdx.y;
    const int wave = blockIdx.x*4 + (threadIdx.x >> 6);   // 0..GSTRIDE-1
    const int lane = threadIdx.x & 63;
    const int nw   = n_work[b];

    const int* __restrict__ P = prefix + b*PREF_STRIDE;
    const float4* __restrict__ R = recs + (long long)b*NPTS;
    float* __restrict__ img = out + (size_t)b*BOX*BOX;
    const float Kc  = -0.32059884f;                // -log2(e)/(2*sig^2)
    const float K8  = 8.0f  * Kc;
    const float K16 = 16.0f * Kc;
    const float C32 = 0.00081582472f;              // 2^(32*Kc)

    for (int it = wave; it < nw; it += GSTRIDE) {
        const int wd   = __builtin_amdgcn_readfirstlane(work[b*WCAP + it]);
        const int cell = wd >> 9, kch = wd & 511;
        const int s = P[cell] + kch*CHUNK;          // scalar (cell uniform)
        const int e = min(P[cell+1], s + CHUNK);

        const int cy = cell >> 6, cx = cell & 63;
        const int col = lane & 15, r0 = lane >> 4;
        const int gx  = 4*cx - 4 + col;
        const int gy0 = 4*cy - 4 + r0;
        const float xf  = (float)gx;
        const float y0f = (float)gy0;
        const float fr0 = (float)r0;
        const float cy4 = (float)(4*cy);

        float a0 = 0.f, a1 = 0.f, a2 = 0.f;
        #pragma unroll 8
        for (int rr = s; rr < e; ++rr) {
            const float4 rc = R[rr];                // uniform addr -> s_load_dwordx4
            const float ry = rc.x, rx = rc.y, ra = rc.z;

            const float dx = xf - rx;
            float aex = ra * exp2f((dx*dx)*Kc);
            aex = (dx > -4.5f && dx <= 4.5f) ? aex : 0.f;

            const float dy = y0f - ry;
            const float e0 = exp2f((dy*dy)*Kc);
            // clamp exponent: no-op for in-cell records (exp <= ~17); prevents
            // inf (and 0*inf=NaN) if a record ever lands wildly out of range
            const float u  = exp2f(fminf(fmaf(dy, K8, K16), 126.f));
            const float e1 = e0 * u;
            const float e2 = e1 * (u * C32);
            const float st = floorf(ry + 0.5f) - cy4;
            const float w0 = (fr0 >= st) ? e0 : 0.f;
            const float w2 = (fr0 <= st) ? e2 : 0.f;
            a0 = fmaf(w0, aex, a0);
            a1 = fmaf(e1, aex, a1);
            a2 = fmaf(w2, aex, a2);
        }

        if (gx >= 0 && gx < BOX) {
            if (a0 != 0.f && gy0 >= 0)      atomicAdd(&img[ gy0     *BOX + gx], a0);
            if (a1 != 0.f)                  atomicAdd(&img[(gy0 + 4)*BOX + gx], a1);
            if (a2 != 0.f && gy0 + 8 < BOX) atomicAdd(&img[(gy0 + 8)*BOX + gx], a2);
        }
    }
}

__global__ __launch_bounds__(256) void copy_img(const float4* __restrict__ src,
                                                float4* __restrict__ dst, int n4)
{
    int i = blockIdx.x*blockDim.x + threadIdx.x;
    if (i < n4) dst[i] = src[i];
}

extern "C" void kernel_launch(void* const* d_in, const int* in_sizes, int n_in,
                              void* d_out, int out_size, void* d_ws, size_t ws_size,
                              hipStream_t stream)
{
    const float* z        = (const float*)d_in[0];
    const float* r        = (const float*)d_in[1];
    const float* posp     = (const float*)d_in[2];
    const float* amp      = (const float*)d_in[3];
    const float* lin0_w   = (const float*)d_in[4];
    const float* deform_w = (const float*)d_in[5];
    const float* deform_b = (const float*)d_in[6];
    const float* lin1a_w  = (const float*)d_in[7];
    const float* lin1b_w  = (const float*)d_in[8];
    const float* linamp_w = (const float*)d_in[9];
    const float* linamp_b = (const float*)d_in[10];
    const int*   dflag    = (const int*)d_in[11];
    float* out = (float*)d_out;

    int* ws_i    = (int*)d_ws;
    int* counts  = ws_i + WS_COUNTS;
    int* n_work  = ws_i + WS_NWORK;
    int* prefix  = ws_i + WS_PREFIX;
    int* work    = ws_i + WS_WORK;
    int* aux     = ws_i + WS_AUX;
    float4* recs = (float4*)((char*)d_ws + (size_t)WS_INTS*sizeof(int));

    hipMemsetAsync(counts, 0, (size_t)(BATCH*CELLS + BATCH)*sizeof(int), stream);
    hipMemsetAsync(out, 0, (size_t)IMG_ELEMS*sizeof(float), stream);

    dim3 gridM(MBLKX, BATCH);
    mlp_bin<<<gridM, MTPB, 0, stream>>>(z, r, posp, amp, lin0_w, deform_w, deform_b,
                                        lin1a_w, lin1b_w, linamp_w, linamp_b, dflag,
                                        out, counts, aux);

    scan_cells<<<BATCH, 1024, 0, stream>>>(counts, prefix, n_work, work);

    dim3 gridP(PBLKX, BATCH);
    place<<<gridP, PTPB, 0, stream>>>(z, amp, linamp_w, linamp_b, out, prefix, aux, recs);

    dim3 gridG(GBLK, BATCH);
    gather_work<<<gridG, 256, 0, stream>>>(recs, prefix, n_work, work, out);

    const int n4 = IMG_ELEMS/4;
    copy_img<<<(n4 + 255)/256, 256, 0, stream>>>((const float4*)out,
                                                 (float4*)(out + OFF_IMG2), n4);
}

// Round 6
// 190.567 us; speedup vs baseline: 1.5446x; 1.1536x over previous
//
#include <hip/hip_runtime.h>
#include <math.h>

#define BOX   256
#define NPTS  50000
#define LATD  10
#define NEUR  32
#define NLAY  3
#define BATCH 16

#define MTPB  256
#define MBLKX ((NPTS + MTPB - 1)/MTPB)     // 196 blocks/image, 1 pt/thread

#define PTPB  256
#define PBLKX ((NPTS + PTPB - 1)/PTPB)     // 196

#define CELLS_X 64                          // 4x4-px cells
#define CELLS   (CELLS_X*CELLS_X)           // 4096
#define PREF_STRIDE 4104
#define CHUNK   128                         // worst-case nw = 4096+391 <= WCAP
#define WCAP    4608

// gather grid: 256 blocks/image * 4 waves = 1024 waves/image
#define GBLK    256
#define GSTRIDE (GBLK*4)

#define IMG_ELEMS (BATCH*BOX*BOX)
#define OFF_IMG2  (IMG_ELEMS)
#define OFF_PROJ  (2*IMG_ELEMS)
#define OFF_POS   (OFF_PROJ + BATCH*NPTS*2)
#define OFF_RES   (OFF_POS  + BATCH*NPTS*3)

// ws ints: counts[16*4096] | n_work[16] | prefix[16*4104] | work[16*4608] | aux[16*50000]
// then (16B aligned): recs float4[16*50000]   -> ~16.8 MB total
#define WS_COUNTS 0
#define WS_NWORK  (BATCH*CELLS)
#define WS_PREFIX (WS_NWORK + BATCH)
#define WS_WORK   (WS_PREFIX + BATCH*PREF_STRIDE)
#define WS_AUX    (WS_WORK + BATCH*WCAP)
#define WS_INTS   (WS_AUX + BATCH*NPTS)

// LDS h-tile row stride in dwords: 32 h cols + pad to 36 (144 B rows, 16B-aligned)
#define HSTR 36

typedef _Float16 f16x8 __attribute__((ext_vector_type(8)));
typedef float    f32x4 __attribute__((ext_vector_type(4)));

// raw v_exp_f32 (inputs bounded; skip OCML range-fixup code)
#if __has_builtin(__builtin_amdgcn_exp2f)
#define EXP2R(x) __builtin_amdgcn_exp2f(x)
#else
#define EXP2R(x) exp2f(x)
#endif

__device__ __forceinline__ float fast_tanh(float x) {
    return 1.0f - 2.0f / (__expf(2.0f * x) + 1.0f);
}

// RNE float->fp16 pack (v_cvt_f16_f32 is RNE; fp16 half-ulp 2^-11 vs bf16 2^-8)
__device__ __forceinline__ f16x8 pack8h(f32x4 a, f32x4 b) {
    f16x8 v;
    v[0] = (_Float16)a[0]; v[1] = (_Float16)a[1];
    v[2] = (_Float16)a[2]; v[3] = (_Float16)a[3];
    v[4] = (_Float16)b[0]; v[5] = (_Float16)b[1];
    v[6] = (_Float16)b[2]; v[7] = (_Float16)b[3];
    return v;
}

// ---- kernel A: fused MLP. lin0 + lin1a/b in VALU; 3 deform layers via
//      mfma_f32_16x16x32_f16 (A row=lane&15 k0=rq*8 from ds_read_b128 pairs,
//      B col=lane&15 preloaded in VGPRs, D: col=lane&15 row=4rq+reg [m89]).
//      Residual kept in REGISTERS across layers (C-layout is elementwise).
__global__ __launch_bounds__(MTPB) void mlp_bin(
    const float* __restrict__ z, const float* __restrict__ r,
    const float* __restrict__ pos_param, const float* __restrict__ amp,
    const float* __restrict__ lin0_w, const float* __restrict__ deform_w,
    const float* __restrict__ deform_b, const float* __restrict__ lin1a_w,
    const float* __restrict__ lin1b_w, const float* __restrict__ linamp_w,
    const float* __restrict__ linamp_b, const int* __restrict__ dflag,
    float* __restrict__ out, int* __restrict__ counts, int* __restrict__ aux)
{
    // 4 wave-private h-tiles [64][HSTR] fp32 + zpart[32]; s_cnt (4096 ints)
    // unioned onto tiles 0/1, used only after all tile reads are done.
    __shared__ __align__(16) float s_mem[4*64*HSTR + NEUR];
    int*   s_cnt = (int*)s_mem;
    float* s_z   = s_mem + 4*64*HSTR;

    const int b     = blockIdx.y;
    const int tid   = threadIdx.x;
    const int wave  = tid >> 6;
    const int lane  = tid & 63;
    const int cfrag = lane & 15;           // A row / B col / D col
    const int rq    = lane >> 4;
    const int k0    = rq * 8;              // fragment K offset
    float* __restrict__ s_hw = s_mem + wave*64*HSTR;

    if (tid < NEUR) {
        float acc = 0.f;
        #pragma unroll
        for (int j = 0; j < LATD-1; j++)
            acc = fmaf(lin0_w[tid*12 + 3 + j], z[b*LATD + j], acc);
        s_z[tid] = acc;
    }
    __syncthreads();

    const int n  = blockIdx.x*MTPB + tid;
    const bool v0 = (n < NPTS);
    const int m0 = v0 ? n : (NPTS-1);
    const int dd = *dflag;

    const float p0w = pos_param[m0*3+0], p1w = pos_param[m0*3+1], p2w = pos_param[m0*3+2];

    float res0 = 0.f, res1 = 0.f, res2 = 0.f;

    if (dd > 0) {
        // ---- preload deform weights as fp16 B-fragments + biases ----
        f16x8 bfrag[NLAY][2];
        float bias_c[NLAY][2];
        #pragma unroll
        for (int l = 0; l < NLAY; ++l) {
            #pragma unroll
            for (int nt = 0; nt < 2; ++nt) {
                const int c = cfrag + 16*nt;
                const float* wp = deform_w + l*NEUR*NEUR + c*NEUR + k0;
                bfrag[l][nt]  = pack8h(*(const f32x4*)wp, *(const f32x4*)(wp + 4));
                bias_c[l][nt] = deform_b[l*NEUR + c];
            }
        }

        // ---- lin0 in VALU: thread writes its own tile row (8 x b128) ----
        #pragma unroll
        for (int o4 = 0; o4 < 8; ++o4) {
            f32x4 hv;
            #pragma unroll
            for (int jj = 0; jj < 4; ++jj) {
                const int o = o4*4 + jj;
                hv[jj] = fmaf(lin0_w[o*12+0], p0w,
                         fmaf(lin0_w[o*12+1], p1w,
                         fmaf(lin0_w[o*12+2], p2w, s_z[o])));
            }
            *(f32x4*)&s_hw[lane*HSTR + o4*4] = hv;
        }
        __syncthreads();

        // ---- one-time C-layout residual read of lin0 output ----
        float rs0[4][4], rs1[4][4];
        #pragma unroll
        for (int mt = 0; mt < 4; ++mt) {
            const int rb = (16*mt + 4*rq)*HSTR + cfrag;
            #pragma unroll
            for (int rr = 0; rr < 4; ++rr) {
                rs0[mt][rr] = s_hw[rb + rr*HSTR];
                rs1[mt][rr] = s_hw[rb + rr*HSTR + 16];
            }
        }

        // ---- 3 residual relu layers via MFMA; residual stays in regs ----
        const f32x4 zc = {0.f, 0.f, 0.f, 0.f};
        #pragma unroll
        for (int l = 0; l < NLAY; ++l) {
            f16x8 af[4];
            #pragma unroll
            for (int mt = 0; mt < 4; ++mt) {
                const float* ap = &s_hw[(16*mt + cfrag)*HSTR + k0];
                af[mt] = pack8h(*(const f32x4*)ap, *(const f32x4*)(ap + 4));
            }
            f32x4 ac0[4], ac1[4];
            #pragma unroll
            for (int mt = 0; mt < 4; ++mt) {
                ac0[mt] = __builtin_amdgcn_mfma_f32_16x16x32_f16(af[mt], bfrag[l][0], zc, 0, 0, 0);
                ac1[mt] = __builtin_amdgcn_mfma_f32_16x16x32_f16(af[mt], bfrag[l][1], zc, 0, 0, 0);
            }
            __syncthreads();               // all tile reads done before overwrite
            const float b0l = bias_c[l][0], b1l = bias_c[l][1];
            #pragma unroll
            for (int mt = 0; mt < 4; ++mt) {
                const int rb = (16*mt + 4*rq)*HSTR + cfrag;
                #pragma unroll
                for (int rr = 0; rr < 4; ++rr) {
                    const float h0n = fmaxf(ac0[mt][rr] + b0l, 0.f) + rs0[mt][rr];
                    const float h1n = fmaxf(ac1[mt][rr] + b1l, 0.f) + rs1[mt][rr];
                    rs0[mt][rr] = h0n;
                    rs1[mt][rr] = h1n;
                    s_hw[rb + rr*HSTR]      = h0n;
                    s_hw[rb + rr*HSTR + 16] = h1n;
                }
            }
            __syncthreads();               // writes visible before next layer reads
        }

        // ---- lin1a + tanh + lin1b in VALU (thread reads its own row) ----
        float t0 = 0.f, t1 = 0.f, t2 = 0.f;
        #pragma unroll
        for (int ch = 0; ch < 8; ++ch) {
            const f32x4 hv = *(const f32x4*)&s_hw[lane*HSTR + ch*4];
            #pragma unroll
            for (int jj = 0; jj < 4; ++jj) {
                const int j = ch*4 + jj;
                t0 = fmaf(lin1a_w[0*NEUR + j], hv[jj], t0);
                t1 = fmaf(lin1a_w[1*NEUR + j], hv[jj], t1);
                t2 = fmaf(lin1a_w[2*NEUR + j], hv[jj], t2);
            }
        }
        t0 = fast_tanh(t0); t1 = fast_tanh(t1); t2 = fast_tanh(t2);
        res0 = fmaf(t0, lin1b_w[0], fmaf(t1, lin1b_w[1], t2*lin1b_w[2]));
        res1 = fmaf(t0, lin1b_w[3], fmaf(t1, lin1b_w[4], t2*lin1b_w[5]));
        res2 = fmaf(t0, lin1b_w[6], fmaf(t1, lin1b_w[7], t2*lin1b_w[8]));
    }

    // ---- epilogue: project, write outputs, bin ----
    const float r00 = r[b*9+0], r01 = r[b*9+1];
    const float r10 = r[b*9+3], r11 = r[b*9+4];
    const float r20 = r[b*9+6], r21 = r[b*9+7];

    int cell = 0;
    if (v0) {
        const float pos0 = p0w + res0, pos1 = p1w + res1, pos2 = p2w + res2;
        const float pj0 = fmaf(pos0, r00, fmaf(pos1, r10, pos2*r20));
        const float pj1 = fmaf(pos0, r01, fmaf(pos1, r11, pos2*r21));
        const long long bn = (long long)b*NPTS + n;
        out[OFF_PROJ + bn*2 + 0] = pj0;  out[OFF_PROJ + bn*2 + 1] = pj1;
        out[OFF_POS  + bn*3 + 0] = pos0; out[OFF_POS  + bn*3 + 1] = pos1;
        out[OFF_POS  + bn*3 + 2] = pos2;
        out[OFF_RES  + bn*3 + 0] = res0; out[OFF_RES + bn*3 + 1] = res1;
        out[OFF_RES  + bn*3 + 2] = res2;
        const float px0 = (pj0 + 0.5f) * (float)(BOX-1);
        const float px1 = (pj1 + 0.5f) * (float)(BOX-1);
        const int c0 = (int)fminf(fmaxf(floorf(px0 + 0.5f), 0.f), 255.f);
        const int c1 = (int)fminf(fmaxf(floorf(px1 + 0.5f), 0.f), 255.f);
        cell = (c0>>2)*CELLS_X + (c1>>2);
    }

    __syncthreads();                       // all h-tile reads done -> reuse as s_cnt
    for (int i = tid; i < CELLS; i += MTPB) s_cnt[i] = 0;
    __syncthreads();
    int rank = 0;
    if (v0) rank = atomicAdd(&s_cnt[cell], 1);
    __syncthreads();
    // claim global bases: one atomic per non-empty cell per block; s_cnt becomes base
    for (int c = tid; c < CELLS; c += MTPB) {
        const int cnt = s_cnt[c];
        if (cnt > 0) s_cnt[c] = atomicAdd(&counts[b*CELLS + c], cnt);
    }
    __syncthreads();
    if (v0) aux[b*NPTS + n] = (cell << 16) | (s_cnt[cell] + rank);
}

// ------- kernel B: prefix scan of 4096 cells per image + fused work-item build -------
__global__ __launch_bounds__(1024) void scan_cells(
    const int* __restrict__ counts, int* __restrict__ prefix,
    int* __restrict__ n_work, int* __restrict__ work)
{
    __shared__ int lds[1024];
    __shared__ int s_nw;
    const int img = blockIdx.x, t = threadIdx.x;
    if (t == 0) s_nw = 0;
    const int4 v = ((const int4*)(counts + img*CELLS))[t];
    const int s0 = v.x, s1 = s0 + v.y, s2 = s1 + v.z, s3 = s2 + v.w;
    lds[t] = s3;
    __syncthreads();
    #pragma unroll 1
    for (int off = 1; off < 1024; off <<= 1) {
        const int add = (t >= off) ? lds[t - off] : 0;
        __syncthreads();
        lds[t] += add;
        __syncthreads();
    }
    const int incl = lds[t];
    const int base = incl - s3;
    ((int4*)(prefix + img*PREF_STRIDE))[t] = make_int4(base, base+s0, base+s1, base+s2);
    if (t == 1023) prefix[img*PREF_STRIDE + CELLS] = incl;

    // fused build_work: each thread owns cells 4t..4t+3 with counts v.x..v.w
    // work item = (cell << 9) | chunk_idx   (chunk_idx < 512 since CHUNK=128)
    const int cnts[4] = { v.x, v.y, v.z, v.w };
    #pragma unroll
    for (int i = 0; i < 4; i++) {
        const int cnt = cnts[i];
        if (cnt > 0) {
            const int c = 4*t + i;
            const int nch = (cnt + CHUNK - 1)/CHUNK;
            const int wb = atomicAdd(&s_nw, nch);
            for (int k = 0; k < nch; k++) work[img*WCAP + wb + k] = (c << 9) | k;
        }
    }
    __syncthreads();
    if (t == 0) n_work[img] = s_nw;
}

// ------- kernel C: place records at final cell-sorted positions -------
__global__ __launch_bounds__(PTPB) void place(
    const float* __restrict__ z, const float* __restrict__ amp,
    const float* __restrict__ linamp_w, const float* __restrict__ linamp_b,
    const float* __restrict__ out, const int* __restrict__ prefix,
    const int* __restrict__ aux, float4* __restrict__ recs)
{
    const int b = blockIdx.y;
    const int n = blockIdx.x*PTPB + threadIdx.x;
    if (n >= NPTS) return;

    const long long bn = (long long)b*NPTS + n;
    const float pj0 = out[OFF_PROJ + bn*2 + 0];
    const float pj1 = out[OFF_PROJ + bn*2 + 1];
    const float lo = fmaf(z[b*LATD + LATD-1], linamp_w[n], linamp_b[n]);
    const float a  = amp[0] / (1.0f + __expf(-lo));
    const float px0 = (pj0 + 0.5f) * (float)(BOX-1);
    const float px1 = (pj1 + 0.5f) * (float)(BOX-1);

    const int av  = aux[b*NPTS + n];
    const int cell = av >> 16, wr = av & 0xFFFF;
    const int dst  = prefix[b*PREF_STRIDE + cell] + wr;
    recs[(long long)b*NPTS + dst] = make_float4(px0, px1, a, 0.f);
}

// -------- kernel D: one wave per chunk; scalar record loads (8-deep);
//          fused radial exp2 (2 transcendentals/record), raw v_exp_f32 --------
__global__ __launch_bounds__(256) void gather_work(
    const float4* __restrict__ recs, const int* __restrict__ prefix,
    const int* __restrict__ n_work, const int* __restrict__ work,
    float* __restrict__ out)
{
    const int b    = blockIdx.y;
    const int wave = blockIdx.x*4 + (threadIdx.x >> 6);   // 0..GSTRIDE-1
    const int lane = threadIdx.x & 63;
    const int nw   = n_work[b];

    const int* __restrict__ P = prefix + b*PREF_STRIDE;
    const float4* __restrict__ R = recs + (long long)b*NPTS;
    float* __restrict__ img = out + (size_t)b*BOX*BOX;
    const float Kc  = -0.32059884f;                // -log2(e)/(2*sig^2)
    const float K8  = 8.0f  * Kc;
    const float K16 = 16.0f * Kc;
    const float C32 = 0.00081582472f;              // 2^(32*Kc)

    for (int it = wave; it < nw; it += GSTRIDE) {
        const int wd   = __builtin_amdgcn_readfirstlane(work[b*WCAP + it]);
        const int cell = wd >> 9, kch = wd & 511;
        const int s = P[cell] + kch*CHUNK;          // scalar (cell uniform)
        const int e = min(P[cell+1], s + CHUNK);

        const int cy = cell >> 6, cx = cell & 63;
        const int col = lane & 15, r0 = lane >> 4;
        const int gx  = 4*cx - 4 + col;
        const int gy0 = 4*cy - 4 + r0;
        const float xf  = (float)gx;
        const float y0f = (float)gy0;
        const float frc = (float)(r0 + 4*cy);       // fr0 + cy4, hoisted

        float a0 = 0.f, a1 = 0.f, a2 = 0.f;
        #pragma unroll 8
        for (int rr = s; rr < e; ++rr) {
            const float4 rc = R[rr];                // uniform addr -> s_load_dwordx4
            const float ry = rc.x, rx = rc.y, ra = rc.z;

            const float dx = xf - rx;
            const float dy = y0f - ry;
            // fused radial gaussian: g = ra * 2^((dx^2+dy^2)*Kc), x-range masked
            const float d2 = fmaf(dy, dy, dx*dx);
            float g = ra * EXP2R(d2 * Kc);
            g = (dx > -4.5f && dx <= 4.5f) ? g : 0.f;

            // row ladder: u = 2^(8*dy*Kc + 16*Kc); rows at dy, dy+4, dy+8
            const float u  = EXP2R(fminf(fmaf(dy, K8, K16), 126.f));
            const float stf = floorf(ry + 0.5f);    // center row (absolute)
            const float uu  = (u * u) * C32;
            const float g0m = (frc >= stf) ? g  : 0.f;
            const float u2m = (frc <= stf) ? uu : 0.f;
            a0 += g0m;
            a1 = fmaf(g, u,   a1);
            a2 = fmaf(g, u2m, a2);
        }

        if (gx >= 0 && gx < BOX) {
            if (a0 != 0.f && gy0 >= 0)      atomicAdd(&img[ gy0     *BOX + gx], a0);
            if (a1 != 0.f)                  atomicAdd(&img[(gy0 + 4)*BOX + gx], a1);
            if (a2 != 0.f && gy0 + 8 < BOX) atomicAdd(&img[(gy0 + 8)*BOX + gx], a2);
        }
    }
}

__global__ __launch_bounds__(256) void copy_img(const float4* __restrict__ src,
                                                float4* __restrict__ dst, int n4)
{
    int i = blockIdx.x*blockDim.x + threadIdx.x;
    if (i < n4) dst[i] = src[i];
}

extern "C" void kernel_launch(void* const* d_in, const int* in_sizes, int n_in,
                              void* d_out, int out_size, void* d_ws, size_t ws_size,
                              hipStream_t stream)
{
    const float* z        = (const float*)d_in[0];
    const float* r        = (const float*)d_in[1];
    const float* posp     = (const float*)d_in[2];
    const float* amp      = (const float*)d_in[3];
    const float* lin0_w   = (const float*)d_in[4];
    const float* deform_w = (const float*)d_in[5];
    const float* deform_b = (const float*)d_in[6];
    const float* lin1a_w  = (const float*)d_in[7];
    const float* lin1b_w  = (const float*)d_in[8];
    const float* linamp_w = (const float*)d_in[9];
    const float* linamp_b = (const float*)d_in[10];
    const int*   dflag    = (const int*)d_in[11];
    float* out = (float*)d_out;

    int* ws_i    = (int*)d_ws;
    int* counts  = ws_i + WS_COUNTS;
    int* n_work  = ws_i + WS_NWORK;
    int* prefix  = ws_i + WS_PREFIX;
    int* work    = ws_i + WS_WORK;
    int* aux     = ws_i + WS_AUX;
    float4* recs = (float4*)((char*)d_ws + (size_t)WS_INTS*sizeof(int));

    hipMemsetAsync(counts, 0, (size_t)(BATCH*CELLS + BATCH)*sizeof(int), stream);
    hipMemsetAsync(out, 0, (size_t)IMG_ELEMS*sizeof(float), stream);

    dim3 gridM(MBLKX, BATCH);
    mlp_bin<<<gridM, MTPB, 0, stream>>>(z, r, posp, amp, lin0_w, deform_w, deform_b,
                                        lin1a_w, lin1b_w, linamp_w, linamp_b, dflag,
                                        out, counts, aux);

    scan_cells<<<BATCH, 1024, 0, stream>>>(counts, prefix, n_work, work);

    dim3 gridP(PBLKX, BATCH);
    place<<<gridP, PTPB, 0, stream>>>(z, amp, linamp_w, linamp_b, out, prefix, aux, recs);

    dim3 gridG(GBLK, BATCH);
    gather_work<<<gridG, 256, 0, stream>>>(recs, prefix, n_work, work, out);

    const int n4 = IMG_ELEMS/4;
    copy_img<<<(n4 + 255)/256, 256, 0, stream>>>((const float4*)out,
                                                 (float4*)(out + OFF_IMG2), n4);
}